// Round 4
// baseline (217.639 us; speedup 1.0000x reference)
//
#include <hip/hip_runtime.h>

#define LRC   0.01f
#define WCLIP 5.0f
#define LO   (-4.5951198501345898f)
#define HI   ( 4.5951198501345898f)

__device__ __forceinline__ unsigned short f2bf(float f) {
    unsigned int u = __float_as_uint(f);
    u += 0x7fffu + ((u >> 16) & 1u);          // RNE
    return (unsigned short)(u >> 16);
}
__device__ __forceinline__ float bflo(unsigned int p) { return __uint_as_float(p << 16); }
__device__ __forceinline__ float bfhi(unsigned int p) { return __uint_as_float(p & 0xffff0000u); }

// ---------------------------------------------------------------------------
// K1: distances GEMM, K-split x2 -> 512 blocks (2 blocks/CU for barrier
//     overlap). Block = 64x64 out-tile over one K=256 half (4 BK-64 tiles),
//     ascending-k fp32 fmaf within the half. Partials -> pd[kh] (carved from
//     outw, which is dead until k2's epilogue).
// ---------------------------------------------------------------------------
__global__ __launch_bounds__(256) void k1_part(
    const float* __restrict__ cmap,    // (4096, 512)
    const float* __restrict__ ctx,     // (512, 256)
    float* __restrict__ pd)            // 2 x (4096, 256) partials
{
    __shared__ __align__(16) float As[64 * 68];   // As[k][m], stride 68
    __shared__ __align__(16) float Bs[64 * 68];   // Bs[k][n], stride 68
    const int t    = threadIdx.x;
    const int tile = blockIdx.x >> 1;
    const int kh   = blockIdx.x & 1;
    const int kbase = kh << 8;

    const int gm = tile >> 2, gn = tile & 3;
    const int m0 = gm << 6, n0 = gn << 6;
    const int tm = t >> 4, tn = t & 15;
    const int rs = t >> 4;             // staging row base
    const int cs = (t & 15) << 2;      // staging 4-col offset

    float acc[4][4];
    #pragma unroll
    for (int i = 0; i < 4; i++)
        #pragma unroll
        for (int j = 0; j < 4; j++) acc[i][j] = 0.f;

    float4 va[4], vb[4];
    #pragma unroll
    for (int rep = 0; rep < 4; rep++) {
        va[rep] = *(const float4*)(cmap + (m0 + (rep << 4) + rs) * 512 + kbase + cs);
        vb[rep] = *(const float4*)(ctx + (kbase + (rep << 4) + rs) * 256 + n0 + cs);
    }

    for (int k0 = kbase; k0 < kbase + 256; k0 += 64) {
        __syncthreads();
        #pragma unroll
        for (int rep = 0; rep < 4; rep++) {
            const int r = (rep << 4) + rs;
            As[(cs + 0) * 68 + r] = va[rep].x;       // A transposed: As[k][m]
            As[(cs + 1) * 68 + r] = va[rep].y;
            As[(cs + 2) * 68 + r] = va[rep].z;
            As[(cs + 3) * 68 + r] = va[rep].w;
            *(float4*)(Bs + r * 68 + cs) = vb[rep];  // B natural: Bs[k][n]
        }
        if (k0 + 64 < kbase + 256) {                 // next tile in flight
            #pragma unroll
            for (int rep = 0; rep < 4; rep++) {
                va[rep] = *(const float4*)(cmap + (m0 + (rep << 4) + rs) * 512 + k0 + 64 + cs);
                vb[rep] = *(const float4*)(ctx + (k0 + 64 + (rep << 4) + rs) * 256 + n0 + cs);
            }
        }
        __syncthreads();

        const float* ap = As + (tm << 2);
        const float* bp = Bs + (tn << 2);
        #pragma unroll 8
        for (int k = 0; k < 64; ++k) {
            float4 a4 = *(const float4*)(ap + k * 68);
            float4 b4 = *(const float4*)(bp + k * 68);
            acc[0][0] = fmaf(a4.x, b4.x, acc[0][0]);
            acc[0][1] = fmaf(a4.x, b4.y, acc[0][1]);
            acc[0][2] = fmaf(a4.x, b4.z, acc[0][2]);
            acc[0][3] = fmaf(a4.x, b4.w, acc[0][3]);
            acc[1][0] = fmaf(a4.y, b4.x, acc[1][0]);
            acc[1][1] = fmaf(a4.y, b4.y, acc[1][1]);
            acc[1][2] = fmaf(a4.y, b4.z, acc[1][2]);
            acc[1][3] = fmaf(a4.y, b4.w, acc[1][3]);
            acc[2][0] = fmaf(a4.z, b4.x, acc[2][0]);
            acc[2][1] = fmaf(a4.z, b4.y, acc[2][1]);
            acc[2][2] = fmaf(a4.z, b4.z, acc[2][2]);
            acc[2][3] = fmaf(a4.z, b4.w, acc[2][3]);
            acc[3][0] = fmaf(a4.w, b4.x, acc[3][0]);
            acc[3][1] = fmaf(a4.w, b4.y, acc[3][1]);
            acc[3][2] = fmaf(a4.w, b4.z, acc[3][2]);
            acc[3][3] = fmaf(a4.w, b4.w, acc[3][3]);
        }
    }
    float* dst = pd + (kh ? (4096 * 256) : 0);
    #pragma unroll
    for (int i = 0; i < 4; i++) {
        float4 v = make_float4(acc[i][0], acc[i][1], acc[i][2], acc[i][3]);
        *(float4*)(dst + (m0 + (tm << 2) + i) * 256 + n0 + (tn << 2)) = v;
    }
}

// ---------------------------------------------------------------------------
// K1b: combine K-halves, compare vs cbias, pack idx bits (blocks 0..255);
//      transpose logits -> lT (blocks 256..319).
// ---------------------------------------------------------------------------
__global__ __launch_bounds__(256) void k1b_idx_lt(
    const float* __restrict__ pd,      // 2 x (4096, 256)
    const float* __restrict__ cbias,   // (4096)
    const float* __restrict__ logits,  // (1024, 256)
    int*   __restrict__ idxb,          // (1024, 256)
    float* __restrict__ lT)            // (256, 1024)
{
    __shared__ float T[64 * 68];
    const int t   = threadIdx.x;
    const int blk = blockIdx.x;

    if (blk < 256) {
        const int sg = (blk << 2) + (t >> 6);         // neuron
        const int c4 = (t & 63) << 2;                 // col base
        int4 iv;
        int* ivp = &iv.x;
        float d[4][4];
        #pragma unroll
        for (int i = 0; i < 4; i++) {                 // 4 context maps
            const int m = (sg << 2) + i;
            float4 p0 = *(const float4*)(pd + m * 256 + c4);
            float4 p1 = *(const float4*)(pd + 4096 * 256 + m * 256 + c4);
            d[i][0] = p0.x + p1.x;
            d[i][1] = p0.y + p1.y;
            d[i][2] = p0.z + p1.z;
            d[i][3] = p0.w + p1.w;
        }
        float cb[4];
        #pragma unroll
        for (int i = 0; i < 4; i++) cb[i] = cbias[(sg << 2) + i];
        #pragma unroll
        for (int j = 0; j < 4; j++) {
            int v = 0;
            #pragma unroll
            for (int i = 0; i < 4; i++)
                v |= (d[i][j] > cb[i]) ? (1 << i) : 0;
            ivp[j] = v;
        }
        *(int4*)(idxb + sg * 256 + c4) = iv;
    } else {
        const int bi = blk - 256;
        const int i0 = (bi >> 2) << 6;
        const int b0 = (bi & 3) << 6;
        #pragma unroll
        for (int rep = 0; rep < 4; rep++) {
            int flat4 = rep * 256 + t;
            int r = flat4 >> 4;                       // i-local
            int c = (flat4 & 15) << 2;                // b-local
            float4 v = *(const float4*)(logits + (i0 + r) * 256 + b0 + c);
            T[(c + 0) * 68 + r] = v.x;
            T[(c + 1) * 68 + r] = v.y;
            T[(c + 2) * 68 + r] = v.z;
            T[(c + 3) * 68 + r] = v.w;
        }
        __syncthreads();
        #pragma unroll
        for (int rep = 0; rep < 4; rep++) {
            int flat4 = rep * 256 + t;
            int r = flat4 >> 4;                       // b-local
            int c = (flat4 & 15) << 2;                // i-local
            *(float4*)(lT + (b0 + r) * 1024 + i0 + c) =
                *(const float4*)(T + r * 68 + c);
        }
    }
}

// ---------------------------------------------------------------------------
// K2: forward dots + sigmoid + last-b coef + fused weight update.
//     512 blocks x 1024 thr: 2 neurons/block -> 2 blocks/CU (32 waves, 100%
//     occupancy) so chunk barriers and the write drain overlap across blocks.
//     Weights staged as bf16 (exact for 1/1024); update re-reads fp32 (L2-hot).
// ---------------------------------------------------------------------------
__global__ __launch_bounds__(1024) void k2_fwd_upd(
    const float* __restrict__ logits,   // (1024, 256)
    const float* __restrict__ targets,  // (256)
    const float* __restrict__ weights,  // (1024, 16, 1024)
    const float* __restrict__ bias,     // (1)
    const int*   __restrict__ idxb,     // (1024, 256)
    const float* __restrict__ lT,       // (256, 1024)
    float* __restrict__ outp,           // d_out first 1024*256
    float* __restrict__ outw)           // d_out + 1024*256
{
    __shared__ unsigned short wlds[32 * 68];   // 2 neurons x 16 rows, bf16
    __shared__ float red[3 * 2 * 256];         // partials from q=1..3
    __shared__ float sig_lds[2 * 256];
    __shared__ int   lastb[32];
    __shared__ float cf_lds[32];

    const int t  = threadIdx.x;
    const int b  = t & 255;
    const int q  = t >> 8;               // i-quarter 0..3
    const int s0 = blockIdx.x << 1;      // 2 neurons/block

    if (t < 32) lastb[t] = -1;

    int jg[2], rowoff[2];
    #pragma unroll
    for (int g = 0; g < 2; g++) {
        jg[g] = idxb[(s0 + g) * 256 + b];
        rowoff[g] = ((g << 4) + jg[g]) * 68;
    }

    // staging: threads 0..511 cover (row r, 4 cols at c) of each 32x64 chunk
    const int r = t >> 4;                // 0..31 (valid when t<512)
    const int c = (t & 15) << 2;
    const float* wsrc = weights + ((s0 + (r >> 4)) << 14) + ((r & 15) << 10) + c;
    const int ldsoff = r * 68 + c;
    const bool stager = (t < 512);

    float4 pf;
    if (stager) pf = *(const float4*)wsrc;   // chunk 0 prefetch

    float acc[2] = {0.f, 0.f};
    const int qq = q << 4;               // i-local base within 64-chunk

    for (int c0 = 0; c0 < 16; ++c0) {
        __syncthreads();                 // previous chunk's readers done
        if (stager) {
            unsigned int p0 = (unsigned int)f2bf(pf.x) | ((unsigned int)f2bf(pf.y) << 16);
            unsigned int p1 = (unsigned int)f2bf(pf.z) | ((unsigned int)f2bf(pf.w) << 16);
            *(uint2*)(wlds + ldsoff) = make_uint2(p0, p1);
            if (c0 < 15) pf = *(const float4*)(wsrc + ((c0 + 1) << 6));  // in flight
        }
        __syncthreads();                 // staged chunk visible

        const int ibase = (c0 << 6) + qq;
        #pragma unroll
        for (int ii = 0; ii < 16; ii += 4) {
            const int i = ibase + ii;
            float l0 = logits[(i + 0) * 256 + b];
            float l1 = logits[(i + 1) * 256 + b];
            float l2 = logits[(i + 2) * 256 + b];
            float l3 = logits[(i + 3) * 256 + b];
            #pragma unroll
            for (int g = 0; g < 2; g++) {
                uint2 wp = *(const uint2*)(wlds + rowoff[g] + qq + ii);
                acc[g] = fmaf(bflo(wp.x), l0, acc[g]);
                acc[g] = fmaf(bfhi(wp.x), l1, acc[g]);
                acc[g] = fmaf(bflo(wp.y), l2, acc[g]);
                acc[g] = fmaf(bfhi(wp.y), l3, acc[g]);
            }
        }
    }

    // reduce i-quarters
    if (q > 0) {
        #pragma unroll
        for (int g = 0; g < 2; g++) red[((q - 1) * 2 + g) * 256 + b] = acc[g];
    }
    __syncthreads();
    if (q == 0) {
        #pragma unroll
        for (int g = 0; g < 2; g++) {
            float tot = acc[g] + red[(0 * 2 + g) * 256 + b]
                               + red[(1 * 2 + g) * 256 + b]
                               + red[(2 * 2 + g) * 256 + b];
            float outv = fminf(fmaxf(tot, LO), HI);
            if (s0 + g == 0) outv = bias[0];      // neuron 0 forced to bias
            outp[(s0 + g) * 256 + b] = outv;
            sig_lds[(g << 8) + b] = 1.f / (1.f + __expf(-outv));
        }
    }
    __syncthreads();
    if (q == 0) {
        #pragma unroll
        for (int g = 0; g < 2; g++)
            atomicMax(&lastb[(g << 4) + jg[g]], b);
    }
    __syncthreads();
    if (t < 32) {
        int g  = t >> 4;
        int bb = lastb[t];
        float cfv = 0.f;
        if (bb >= 0) cfv = LRC * (sig_lds[(g << 8) + bb] - targets[bb]);
        cf_lds[t] = cfv;
    }
    __syncthreads();

    // ---- fused update epilogue: 32 rows x 1024 cols, fp32-exact ----
    const int er = t >> 5;               // row 0..31 = g*16 + j
    const int ec = (t & 31) << 2;        // col base 0..124
    const long rowbase = ((long)(s0 + (er >> 4)) << 14) + ((long)(er & 15) << 10);
    const int   col = lastb[er];         // uniform within 32-lane row group
    const float cf  = cf_lds[er];
    const float* lrow = lT + ((long)(col < 0 ? 0 : col) << 10);
    #pragma unroll 4
    for (int seg = 0; seg < 8; ++seg) {
        const int c2 = ec + (seg << 7);
        float4 wv = *(const float4*)(weights + rowbase + c2);
        float4 res = wv;                 // untouched row: verbatim copy
        if (col >= 0) {
            float4 lv = *(const float4*)(lrow + c2);
            res.x = fminf(fmaxf(wv.x - cf * lv.x, -WCLIP), WCLIP);
            res.y = fminf(fmaxf(wv.y - cf * lv.y, -WCLIP), WCLIP);
            res.z = fminf(fmaxf(wv.z - cf * lv.z, -WCLIP), WCLIP);
            res.w = fminf(fmaxf(wv.w - cf * lv.w, -WCLIP), WCLIP);
        }
        *(float4*)(outw + rowbase + c2) = res;
    }
}

// ---------------------------------------------------------------------------
extern "C" void kernel_launch(void* const* d_in, const int* in_sizes, int n_in,
                              void* d_out, int out_size, void* d_ws, size_t ws_size,
                              hipStream_t stream) {
    const float* logits  = (const float*)d_in[0];   // (1024, 256)
    const float* ctx     = (const float*)d_in[1];   // (512, 256)
    const float* targets = (const float*)d_in[2];   // (256)
    const float* weights = (const float*)d_in[3];   // (1024, 16, 1024)
    const float* cmap    = (const float*)d_in[4];   // (1024, 4, 512)
    const float* cbias   = (const float*)d_in[5];   // (1024, 4, 1)
    const float* bias    = (const float*)d_in[6];   // (1)

    float* outp = (float*)d_out;                    // (1024, 256)
    float* outw = outp + 1024 * 256;                // (1024, 16, 1024)

    char* ws = (char*)d_ws;
    int*   idxb = (int*)ws;                         // 1 MB
    float* lT   = (float*)(ws + (1 << 20));         // 1 MB

    // K1 partials live in outw's first 8 MB — dead until k2's epilogue.
    float* pd = outw;

    k1_part   <<<512, 256, 0, stream>>>(cmap, ctx, pd);
    k1b_idx_lt<<<320, 256, 0, stream>>>(pd, cbias, logits, idxb, lT);
    k2_fwd_upd<<<512, 1024, 0, stream>>>(logits, targets, weights, bias, idxb,
                                         lT, outp, outw);
}

// Round 5
// 198.947 us; speedup vs baseline: 1.0940x; 1.0940x over previous
//
#include <hip/hip_runtime.h>

#define LRC   0.01f
#define WCLIP 5.0f
#define LO   (-4.5951198501345898f)
#define HI   ( 4.5951198501345898f)

__device__ __forceinline__ unsigned short f2bf(float f) {
    unsigned int u = __float_as_uint(f);
    u += 0x7fffu + ((u >> 16) & 1u);          // RNE
    return (unsigned short)(u >> 16);
}
__device__ __forceinline__ float bflo(unsigned int p) { return __uint_as_float(p << 16); }
__device__ __forceinline__ float bfhi(unsigned int p) { return __uint_as_float(p & 0xffff0000u); }

// ---------------------------------------------------------------------------
// K1: distances GEMM, 4-way K-split -> 1024 blocks (4 blocks/CU, 16 waves/CU:
//     barrier drains overlap ACROSS blocks). Block = 64x64 out-tile over one
//     K=128 quarter (2 BK-64 tiles, prefetched). Partials -> pd[kq] (carved
//     from outw, dead until k2b). Blocks 1024..1087: logits transpose -> lT.
// ---------------------------------------------------------------------------
__global__ __launch_bounds__(256) void k1_part(
    const float* __restrict__ cmap,    // (4096, 512)
    const float* __restrict__ ctx,     // (512, 256)
    const float* __restrict__ logits,  // (1024, 256)
    float* __restrict__ pd,            // 4 x (4096, 256) partials
    float* __restrict__ lT)            // (256, 1024)
{
    __shared__ __align__(16) float As[64 * 68];   // As[k][m], stride 68
    __shared__ __align__(16) float Bs[64 * 68];   // Bs[k][n], stride 68
    const int t   = threadIdx.x;
    const int blk = blockIdx.x;

    if (blk < 1024) {
        const int tile  = blk >> 2;
        const int kq    = blk & 3;
        const int kbase = kq << 7;            // K quarter of 128

        const int gm = tile >> 2, gn = tile & 3;
        const int m0 = gm << 6, n0 = gn << 6;
        const int tm = t >> 4, tn = t & 15;
        const int rs = t >> 4;                // staging row base
        const int cs = (t & 15) << 2;         // staging 4-col offset

        float acc[4][4];
        #pragma unroll
        for (int i = 0; i < 4; i++)
            #pragma unroll
            for (int j = 0; j < 4; j++) acc[i][j] = 0.f;

        float4 va[4], vb[4];
        #pragma unroll
        for (int rep = 0; rep < 4; rep++) {
            va[rep] = *(const float4*)(cmap + (m0 + (rep << 4) + rs) * 512 + kbase + cs);
            vb[rep] = *(const float4*)(ctx + (kbase + (rep << 4) + rs) * 256 + n0 + cs);
        }

        for (int k0 = kbase; k0 < kbase + 128; k0 += 64) {
            __syncthreads();
            #pragma unroll
            for (int rep = 0; rep < 4; rep++) {
                const int r = (rep << 4) + rs;
                As[(cs + 0) * 68 + r] = va[rep].x;       // A transposed
                As[(cs + 1) * 68 + r] = va[rep].y;
                As[(cs + 2) * 68 + r] = va[rep].z;
                As[(cs + 3) * 68 + r] = va[rep].w;
                *(float4*)(Bs + r * 68 + cs) = vb[rep];  // B natural
            }
            if (k0 + 64 < kbase + 128) {                 // next tile in flight
                #pragma unroll
                for (int rep = 0; rep < 4; rep++) {
                    va[rep] = *(const float4*)(cmap + (m0 + (rep << 4) + rs) * 512 + k0 + 64 + cs);
                    vb[rep] = *(const float4*)(ctx + (k0 + 64 + (rep << 4) + rs) * 256 + n0 + cs);
                }
            }
            __syncthreads();

            const float* ap = As + (tm << 2);
            const float* bp = Bs + (tn << 2);
            #pragma unroll 8
            for (int k = 0; k < 64; ++k) {
                float4 a4 = *(const float4*)(ap + k * 68);
                float4 b4 = *(const float4*)(bp + k * 68);
                acc[0][0] = fmaf(a4.x, b4.x, acc[0][0]);
                acc[0][1] = fmaf(a4.x, b4.y, acc[0][1]);
                acc[0][2] = fmaf(a4.x, b4.z, acc[0][2]);
                acc[0][3] = fmaf(a4.x, b4.w, acc[0][3]);
                acc[1][0] = fmaf(a4.y, b4.x, acc[1][0]);
                acc[1][1] = fmaf(a4.y, b4.y, acc[1][1]);
                acc[1][2] = fmaf(a4.y, b4.z, acc[1][2]);
                acc[1][3] = fmaf(a4.y, b4.w, acc[1][3]);
                acc[2][0] = fmaf(a4.z, b4.x, acc[2][0]);
                acc[2][1] = fmaf(a4.z, b4.y, acc[2][1]);
                acc[2][2] = fmaf(a4.z, b4.z, acc[2][2]);
                acc[2][3] = fmaf(a4.z, b4.w, acc[2][3]);
                acc[3][0] = fmaf(a4.w, b4.x, acc[3][0]);
                acc[3][1] = fmaf(a4.w, b4.y, acc[3][1]);
                acc[3][2] = fmaf(a4.w, b4.z, acc[3][2]);
                acc[3][3] = fmaf(a4.w, b4.w, acc[3][3]);
            }
        }
        float* dst = pd + (long)kq * (4096 * 256);
        #pragma unroll
        for (int i = 0; i < 4; i++) {
            float4 v = make_float4(acc[i][0], acc[i][1], acc[i][2], acc[i][3]);
            *(float4*)(dst + (m0 + (tm << 2) + i) * 256 + n0 + (tn << 2)) = v;
        }
    } else {
        // transpose one 64(i) x 64(b) tile of logits into lT
        float* T = As;
        const int bi = blk - 1024;
        const int i0 = (bi >> 2) << 6;
        const int b0 = (bi & 3) << 6;
        #pragma unroll
        for (int rep = 0; rep < 4; rep++) {
            int flat4 = rep * 256 + t;
            int r = flat4 >> 4;                       // i-local
            int c = (flat4 & 15) << 2;                // b-local
            float4 v = *(const float4*)(logits + (i0 + r) * 256 + b0 + c);
            T[(c + 0) * 68 + r] = v.x;
            T[(c + 1) * 68 + r] = v.y;
            T[(c + 2) * 68 + r] = v.z;
            T[(c + 3) * 68 + r] = v.w;
        }
        __syncthreads();
        #pragma unroll
        for (int rep = 0; rep < 4; rep++) {
            int flat4 = rep * 256 + t;
            int r = flat4 >> 4;                       // b-local
            int c = (flat4 & 15) << 2;                // i-local
            *(float4*)(lT + (b0 + r) * 1024 + i0 + c) =
                *(const float4*)(T + r * 68 + c);
        }
    }
}

// ---------------------------------------------------------------------------
// K2a: idx (from pd) + forward dots + sigmoid + last-b coef.
//      256 blocks x 1024 thr, 4 neurons/block. Weights staged bf16 in TWO
//      512-i mega-chunks (64 KB LDS exactly, XOR-swizzle i^(8j) -> gather on
//      >=8 distinct banks, 2-way max = free). 4 barriers total; chunk-2 loads
//      prefetched into registers BEFORE chunk-1 compute (HBM overlaps FMA).
//      Epilogue arrays alias wlds (all gathers done by then).
// ---------------------------------------------------------------------------
__global__ __launch_bounds__(1024, 4) void k2a_fwd(
    const float* __restrict__ logits,   // (1024, 256)
    const float* __restrict__ targets,  // (256)
    const float* __restrict__ weights,  // (1024, 16, 1024)
    const float* __restrict__ bias,     // (1)
    const float* __restrict__ cbias,    // (4096)
    const float* __restrict__ pd,       // 4 x (4096, 256)
    float* __restrict__ outp,           // d_out first 1024*256
    float* __restrict__ coefb,          // (16384) ws
    int*   __restrict__ colb)           // (16384) ws
{
    __shared__ __align__(16) unsigned short wlds[64 * 512];   // 64 KB
    // aliases, valid only after the final gather barrier:
    float* red  = (float*)wlds;               // [ (q-1)*4+g ][256]  12 KB
    float* sig  = (float*)wlds + 3072;        // [g][256]            4 KB
    int*   lastb = (int*)((float*)wlds + 4096);  // [64]

    const int t  = threadIdx.x;
    const int b  = t & 255;
    const int q  = t >> 8;                // i-quarter (128 i per chunk-half)
    const int s0 = blockIdx.x << 2;

    // ---- staging geometry: thread covers (row r, cols c+seg*64) ----
    const int r  = t >> 4;                // 0..63 = g*16 + j
    const int c  = (t & 15) << 2;         // 0..60
    const float* wsrc = weights + ((s0 + (r >> 4)) << 14) + ((r & 15) << 10) + c;
    const int swz     = (r & 15) << 3;    // staging swizzle = 8*j
    const int ldsbase = r << 9;           // r*512

    // ---- chunk 0 global loads (in flight during idx prologue) ----
    float4 pf[8];
    #pragma unroll
    for (int seg = 0; seg < 8; ++seg)
        pf[seg] = *(const float4*)(wsrc + (seg << 6));

    // ---- idx from k1 partials (fp32, 4-way fold) ----
    int jg[4], rowoff[4], gswz[4];
    #pragma unroll
    for (int g = 0; g < 4; g++) {
        int v = 0;
        #pragma unroll
        for (int mm = 0; mm < 4; mm++) {
            const float* pp = pd + ((s0 + g) * 4 + mm) * 256 + b;
            float d = ((pp[0] + pp[4096 * 256]) + pp[2 * 4096 * 256]) + pp[3 * 4096 * 256];
            v |= (d > cbias[(s0 + g) * 4 + mm]) ? (1 << mm) : 0;
        }
        jg[g] = v;
        rowoff[g] = ((g << 4) + v) << 9;  // row * 512
        gswz[g]   = v << 3;               // gather swizzle = 8*j
    }

    // ---- write chunk 0 to LDS ----
    #pragma unroll
    for (int seg = 0; seg < 8; ++seg) {
        unsigned int p0 = (unsigned int)f2bf(pf[seg].x) | ((unsigned int)f2bf(pf[seg].y) << 16);
        unsigned int p1 = (unsigned int)f2bf(pf[seg].z) | ((unsigned int)f2bf(pf[seg].w) << 16);
        *(uint2*)(wlds + ldsbase + (((seg << 6) + c) ^ swz)) = make_uint2(p0, p1);
    }
    __syncthreads();

    // ---- prefetch chunk 1 into regs (HBM overlaps chunk-0 compute) ----
    #pragma unroll
    for (int seg = 0; seg < 8; ++seg)
        pf[seg] = *(const float4*)(wsrc + 512 + (seg << 6));

    float acc[4] = {0.f, 0.f, 0.f, 0.f};
    const int qq = q << 7;                // 128-i quarter within chunk

    // ---- compute chunk 0 (i global 0..511) ----
    #pragma unroll 4
    for (int ii = 0; ii < 128; ii += 8) {
        const int il = qq + ii;
        float l[8];
        #pragma unroll
        for (int u = 0; u < 8; ++u) l[u] = logits[(il + u) * 256 + b];
        #pragma unroll
        for (int g = 0; g < 4; g++) {
            uint4 wp = *(const uint4*)(wlds + rowoff[g] + (il ^ gswz[g]));
            acc[g] = fmaf(bflo(wp.x), l[0], acc[g]);
            acc[g] = fmaf(bfhi(wp.x), l[1], acc[g]);
            acc[g] = fmaf(bflo(wp.y), l[2], acc[g]);
            acc[g] = fmaf(bfhi(wp.y), l[3], acc[g]);
            acc[g] = fmaf(bflo(wp.z), l[4], acc[g]);
            acc[g] = fmaf(bfhi(wp.z), l[5], acc[g]);
            acc[g] = fmaf(bflo(wp.w), l[6], acc[g]);
            acc[g] = fmaf(bfhi(wp.w), l[7], acc[g]);
        }
    }
    __syncthreads();

    // ---- write chunk 1 to LDS ----
    #pragma unroll
    for (int seg = 0; seg < 8; ++seg) {
        unsigned int p0 = (unsigned int)f2bf(pf[seg].x) | ((unsigned int)f2bf(pf[seg].y) << 16);
        unsigned int p1 = (unsigned int)f2bf(pf[seg].z) | ((unsigned int)f2bf(pf[seg].w) << 16);
        *(uint2*)(wlds + ldsbase + (((seg << 6) + c) ^ swz)) = make_uint2(p0, p1);
    }
    __syncthreads();

    // ---- compute chunk 1 (i global 512..1023) ----
    #pragma unroll 4
    for (int ii = 0; ii < 128; ii += 8) {
        const int il = qq + ii;
        float l[8];
        #pragma unroll
        for (int u = 0; u < 8; ++u) l[u] = logits[(512 + il + u) * 256 + b];
        #pragma unroll
        for (int g = 0; g < 4; g++) {
            uint4 wp = *(const uint4*)(wlds + rowoff[g] + (il ^ gswz[g]));
            acc[g] = fmaf(bflo(wp.x), l[0], acc[g]);
            acc[g] = fmaf(bfhi(wp.x), l[1], acc[g]);
            acc[g] = fmaf(bflo(wp.y), l[2], acc[g]);
            acc[g] = fmaf(bfhi(wp.y), l[3], acc[g]);
            acc[g] = fmaf(bflo(wp.z), l[4], acc[g]);
            acc[g] = fmaf(bfhi(wp.z), l[5], acc[g]);
            acc[g] = fmaf(bflo(wp.w), l[6], acc[g]);
            acc[g] = fmaf(bfhi(wp.w), l[7], acc[g]);
        }
    }
    __syncthreads();                      // all gathers done -> aliases valid

    // ---- epilogue: reduce quarters, sigmoid, last-b coef ----
    if (t < 64) lastb[t] = -1;            // disjoint from red/sig regions
    if (q > 0) {
        #pragma unroll
        for (int g = 0; g < 4; g++) red[((q - 1) * 4 + g) * 256 + b] = acc[g];
    }
    __syncthreads();
    if (q == 0) {
        #pragma unroll
        for (int g = 0; g < 4; g++) {
            float tot = acc[g] + red[(0 * 4 + g) * 256 + b]
                               + red[(1 * 4 + g) * 256 + b]
                               + red[(2 * 4 + g) * 256 + b];
            float outv = fminf(fmaxf(tot, LO), HI);
            if (s0 + g == 0) outv = bias[0];      // neuron 0 forced to bias
            outp[(s0 + g) * 256 + b] = outv;
            sig[(g << 8) + b] = 1.f / (1.f + __expf(-outv));
        }
    }
    __syncthreads();
    if (q == 0) {
        #pragma unroll
        for (int g = 0; g < 4; g++)
            atomicMax(&lastb[(g << 4) + jg[g]], b);
    }
    __syncthreads();
    if (t < 64) {
        int g  = t >> 4;
        int bb = lastb[t];
        float cfv = 0.f;
        if (bb >= 0) cfv = LRC * (sig[(g << 8) + bb] - targets[bb]);
        coefb[(s0 << 4) + t] = cfv;
        colb [(s0 << 4) + t] = bb;
    }
}

// ---------------------------------------------------------------------------
// K2b: streaming update  new_w = clamp(w - coef*lT[b*], +-5)  (or copy).
//      4096 blocks x 256 thr (16 small blocks/CU -> HBM saturation).
// ---------------------------------------------------------------------------
__global__ __launch_bounds__(256) void k2b_update(
    const float* __restrict__ weights,
    const float* __restrict__ lT,
    const float* __restrict__ coefb,
    const int*   __restrict__ colb,
    float* __restrict__ outw)
{
    const int t  = threadIdx.x;
    const int r0 = blockIdx.x << 2;
    const int o  = t << 2;
    #pragma unroll
    for (int rr = 0; rr < 4; rr++) {
        const int row = r0 + rr;
        const int col = colb[row];        // uniform across block
        const float cf = coefb[row];
        float4 wv = *(const float4*)(weights + (long)row * 1024 + o);
        float4 res = wv;                  // untouched row: verbatim copy
        if (col >= 0) {
            float4 lv = *(const float4*)(lT + (long)col * 1024 + o);
            res.x = fminf(fmaxf(wv.x - cf * lv.x, -WCLIP), WCLIP);
            res.y = fminf(fmaxf(wv.y - cf * lv.y, -WCLIP), WCLIP);
            res.z = fminf(fmaxf(wv.z - cf * lv.z, -WCLIP), WCLIP);
            res.w = fminf(fmaxf(wv.w - cf * lv.w, -WCLIP), WCLIP);
        }
        *(float4*)(outw + (long)row * 1024 + o) = res;
    }
}

// ---------------------------------------------------------------------------
extern "C" void kernel_launch(void* const* d_in, const int* in_sizes, int n_in,
                              void* d_out, int out_size, void* d_ws, size_t ws_size,
                              hipStream_t stream) {
    const float* logits  = (const float*)d_in[0];   // (1024, 256)
    const float* ctx     = (const float*)d_in[1];   // (512, 256)
    const float* targets = (const float*)d_in[2];   // (256)
    const float* weights = (const float*)d_in[3];   // (1024, 16, 1024)
    const float* cmap    = (const float*)d_in[4];   // (1024, 4, 512)
    const float* cbias   = (const float*)d_in[5];   // (1024, 4, 1)
    const float* bias    = (const float*)d_in[6];   // (1)

    float* outp = (float*)d_out;                    // (1024, 256)
    float* outw = outp + 1024 * 256;                // (1024, 16, 1024)

    char* ws = (char*)d_ws;
    float* lT    = (float*)ws;                      // 1 MB
    float* coefb = (float*)(ws + (1 << 20));        // 64 KB
    int*   colb  = (int*)  (ws + (1 << 20) + (1 << 16));

    // K1 partials: 4 x 4 MB = 16 MB carved from outw (dead until k2b writes).
    float* pd = outw;

    k1_part   <<<1088, 256, 0, stream>>>(cmap, ctx, logits, pd, lT);
    k2a_fwd   <<<256, 1024, 0, stream>>>(logits, targets, weights, bias,
                                         cbias, pd, outp, coefb, colb);
    k2b_update<<<4096, 256, 0, stream>>>(weights, lT, coefb, colb, outw);
}